// Round 19
// baseline (166.877 us; speedup 1.0000x reference)
//
#include <hip/hip_runtime.h>

#define NPTS 8192
#define DIM  128
#define NCLS 64
#define NT   64
#define NTILES (NT * (NT + 1) / 2)   // 2080 triangular tiles
#define CCAP 256                     // static per-class member capacity (max n ~175)
#define FEPS 1e-16f

typedef float f32x4 __attribute__((ext_vector_type(4)));
typedef unsigned long long ull;

// ws layout (float elements). Kernels init all state (no host memset).
#define WS_T     0          // 8192 floats: T_i (label-blind row sums)
#define WS_CNT   8192       // 64 ints
#define WS_LOSS  8256       // 1 float
#define WS_DONE  8257       // 1 uint
#define WS_SQ    8258       // 8192 floats
#define WS_MEM2  16450      // 64*256 ints
#define WS_SRANK 32834      // 64*256 floats: S by (class, rank)
#define WS_G16A  49220      // 16B aligned; 1MB fp8 swizzled features
#define WS_DP    311364     // ~1.1M floats: per-class distances, row-major a*n+b

__device__ inline float fast_sqrt(float x) {
    float r;
    asm("v_sqrt_f32 %0, %1" : "=v"(r) : "v"(x));
    return r;
}

// ---- node 1: class bucketing (blocks 0..63) + prep (blocks 64..1087) ----
__global__ void prep_bucket_kernel(const float* __restrict__ feat,
                                   const int* __restrict__ labels,
                                   float* __restrict__ sq,
                                   unsigned char* __restrict__ G,
                                   float* __restrict__ T,
                                   int* __restrict__ cnt,
                                   int* __restrict__ mem2,
                                   float* __restrict__ loss_sum,
                                   unsigned int* __restrict__ done) {
    __shared__ int llab[NPTS];
    __shared__ int scan_arr[256];
    __shared__ int wsum[4];

    const int tid = threadIdx.x;
    const int w = tid >> 6, lane = tid & 63;

    if (blockIdx.x >= NCLS) {
        const int kl = lane & 31;
        const int rloc = lane >> 5;
        int i = (blockIdx.x - NCLS) * 8 + w * 2 + rloc;
        float4 v = ((const float4*)(feat + (size_t)i * DIM))[kl];
        unsigned lo = (unsigned)__builtin_amdgcn_cvt_pk_fp8_f32(v.x, v.y, 0, false) & 0xffffu;
        unsigned hi = (unsigned)__builtin_amdgcn_cvt_pk_fp8_f32(v.z, v.w, 0, false);
        unsigned word = lo | (hi << 16);
        int t = i >> 7, m = i & 127;
        int c = kl >> 1, pos = (kl & 1) * 4;
        *(unsigned*)&G[(size_t)t * 16384 + c * 1024 + m * 8 + pos] = word;
        float s = v.x * v.x + v.y * v.y + v.z * v.z + v.w * v.w;
#pragma unroll
        for (int msk = 1; msk <= 16; msk <<= 1) s += __shfl_xor(s, msk, 64);
        if (kl == 0) sq[i] = s;
        if (tid < 8) T[(blockIdx.x - NCLS) * 8 + tid] = 0.0f;
        return;
    }

    const int c = blockIdx.x;
    {
        const uint4* L4 = (const uint4*)labels;
        uint4* S4 = (uint4*)llab;
#pragma unroll
        for (int k = 0; k < 8; ++k) S4[k * 256 + tid] = L4[k * 256 + tid];
    }
    if (c == 0 && tid == 0) { loss_sum[0] = 0.0f; done[0] = 0u; }
    __syncthreads();

    int cntloc = 0;
#pragma unroll
    for (int k = 0; k < 32; ++k) cntloc += (llab[tid + 256 * k] == c) ? 1 : 0;
    scan_arr[tid] = cntloc;
    __syncthreads();

    int v = scan_arr[tid];
    int incl = v;
#pragma unroll
    for (int o = 1; o < 64; o <<= 1) {
        int t1 = __shfl_up(incl, o, 64);
        if (lane >= o) incl += t1;
    }
    if (lane == 63) wsum[w] = incl;
    __syncthreads();
    int wpre = 0;
#pragma unroll
    for (int ww = 0; ww < 4; ++ww) if (ww < w) wpre += wsum[ww];
    int excl = wpre + incl - v;

    int r = excl;
#pragma unroll
    for (int k = 0; k < 32; ++k) {
        int idx = tid + 256 * k;
        if (llab[idx] == c) {
            mem2[c * CCAP + r] = idx;
            ++r;
        }
    }
    if (tid == 255) cnt[c] = excl + v;
}

// ---- node 2: triangular N^2 pass, label-blind T (R18 proven) ----
__launch_bounds__(256, 4)
__global__ void gemm_T(const unsigned char* __restrict__ Gb,
                       const float* __restrict__ sq,
                       float* __restrict__ T) {
    int p = blockIdx.x;
    float disc = 64.5f * 64.5f - 2.0f * (float)p;
    int bt = (int)(64.5f - fast_sqrt(disc));
    if (bt < 0) bt = 0; if (bt > 63) bt = 63;
    while (bt > 0 && (bt * NT - (bt * (bt - 1)) / 2) > p) --bt;
    while (((bt + 1) * NT - ((bt + 1) * bt) / 2) <= p) ++bt;
    int jt = bt + (p - (bt * NT - (bt * (bt - 1)) / 2));

    __shared__ float sqi[128], sqj[128];

    const int tid = threadIdx.x;
    const int w = tid >> 6, lane = tid & 63;
    const int wr = w >> 1, wc = w & 1;
    const int q = lane >> 4, ml = lane & 15;
    const int ib = bt * 128, jb = jt * 128;
    const bool diag = (bt == jt);

    if (tid < 128) sqi[tid] = sq[ib + tid];
    else sqj[tid - 128] = sq[jb + tid - 128];
    __syncthreads();

    const long* A8 = (const long*)(Gb + (size_t)bt * 16384);
    const long* B8 = (const long*)(Gb + (size_t)jt * 16384);

    f32x4 acc[4][4];
#pragma unroll
    for (int a = 0; a < 4; ++a)
#pragma unroll
        for (int b = 0; b < 4; ++b) acc[a][b] = (f32x4){0.f, 0.f, 0.f, 0.f};

#pragma unroll
    for (int s = 0; s < 4; ++s) {
        long af[4], bf[4];
        int kbase = (s * 4 + q) * 128;
#pragma unroll
        for (int ii = 0; ii < 4; ++ii) af[ii] = A8[kbase + wr * 64 + ii * 16 + ml];
#pragma unroll
        for (int jj = 0; jj < 4; ++jj) bf[jj] = B8[kbase + wc * 64 + jj * 16 + ml];
#pragma unroll
        for (int ii = 0; ii < 4; ++ii)
#pragma unroll
            for (int jj = 0; jj < 4; ++jj)
                acc[ii][jj] = __builtin_amdgcn_mfma_f32_16x16x32_fp8_fp8(af[ii], bf[jj], acc[ii][jj], 0, 0, 0);
    }

    int cl[4]; float sj[4];
#pragma unroll
    for (int jj = 0; jj < 4; ++jj) {
        cl[jj] = wc * 64 + jj * 16 + ml;
        sj[jj] = sqj[cl[jj]];
    }
    float colsum[4] = {0.f, 0.f, 0.f, 0.f};

#pragma unroll
    for (int ii = 0; ii < 4; ++ii) {
        int rl = wr * 64 + ii * 16 + q * 4;
        float si4[4];
#pragma unroll
        for (int r = 0; r < 4; ++r) si4[r] = sqi[rl + r];
        float rs[4] = {0.f, 0.f, 0.f, 0.f};
#pragma unroll
        for (int jj = 0; jj < 4; ++jj)
#pragma unroll
            for (int r = 0; r < 4; ++r) {
                float d2 = fmaf(-2.0f, acc[ii][jj][r], si4[r] + sj[jj]);
                float d = fast_sqrt(fmaxf(d2, FEPS));
                float e = __expf(1.0f - d);
                if (diag && (rl + r == cl[jj])) e = 0.0f;
                rs[r] += e;
                colsum[jj] += e;
            }
#pragma unroll
        for (int m = 1; m < 16; m <<= 1)
#pragma unroll
            for (int r = 0; r < 4; ++r) rs[r] += __shfl_xor(rs[r], m, 64);
        if (ml == 0) {
#pragma unroll
            for (int r = 0; r < 4; ++r) atomicAdd(&T[ib + rl + r], rs[r]);
        }
    }
    if (!diag) {
#pragma unroll
        for (int m = 16; m < 64; m <<= 1)
#pragma unroll
            for (int jj = 0; jj < 4; ++jj) colsum[jj] += __shfl_xor(colsum[jj], m, 64);
        if (q == 0) {
#pragma unroll
            for (int jj = 0; jj < 4; ++jj)
                atomicAdd(&T[jb + cl[jj]], colsum[jj]);
        }
    }
}

// ---- node 3: per-class Gram tiles -> distance matrix (no atomics/reductions) ----
__global__ void pairD_kernel(const unsigned char* __restrict__ Gb,
                             const float* __restrict__ sq,
                             const int* __restrict__ cnt,
                             const int* __restrict__ mem2,
                             float* __restrict__ dpair) {
    const int c = blockIdx.x >> 2, t = blockIdx.x & 3;
    const int ta = t >> 1, tb = t & 1;
    const int n = cnt[c];
    const int nt = (n + 127) >> 7;
    if (ta >= nt || tb >= nt) return;

    __shared__ ull Af[16 * 128], Bf[16 * 128];   // 16 KB each, [chunk][row]
    __shared__ float sqa[128], sqb[128];
    __shared__ int s_pb;

    const int tid = threadIdx.x;
    const int w = tid >> 6, lane = tid & 63;
    const int wr = w >> 1, wc = w & 1;
    const int q = lane >> 4, ml = lane & 15;

    {
        const int row = tid & 127, half = tid >> 7;
        const ull* GA = (const ull*)Gb;
        int ra = ta * 128 + row;
        bool va = ra < n;
        int ia = va ? mem2[c * CCAP + ra] : 0;
        size_t basea = (size_t)(ia >> 7) * 2048 + (ia & 127);
        int rb = tb * 128 + row;
        bool vb = rb < n;
        int ib = vb ? mem2[c * CCAP + rb] : 0;
        size_t baseb = (size_t)(ib >> 7) * 2048 + (ib & 127);
#pragma unroll
        for (int k = 0; k < 8; ++k) {
            int ch = half * 8 + k;
            Af[ch * 128 + row] = va ? GA[basea + (size_t)ch * 128] : 0ull;
            Bf[ch * 128 + row] = vb ? GA[baseb + (size_t)ch * 128] : 0ull;
        }
        if (half == 0) { sqa[row] = va ? sq[ia] : 0.f; sqb[row] = vb ? sq[ib] : 0.f; }
    }
    if (w == 0) {                      // wave 0: poff scan
        int v = cnt[lane];
        int v2 = v * v, s2 = v2;
#pragma unroll
        for (int o = 1; o < 64; o <<= 1) {
            int t2 = __shfl_up(s2, o, 64);
            if (lane >= o) s2 += t2;
        }
        if (lane == c) s_pb = s2 - v2;
    }
    __syncthreads();

    f32x4 acc[4][4];
#pragma unroll
    for (int a = 0; a < 4; ++a)
#pragma unroll
        for (int b = 0; b < 4; ++b) acc[a][b] = (f32x4){0.f, 0.f, 0.f, 0.f};

#pragma unroll
    for (int s = 0; s < 4; ++s) {
        long af[4], bf[4];
        int ch = s * 4 + q;
#pragma unroll
        for (int ii = 0; ii < 4; ++ii) af[ii] = (long)Af[ch * 128 + wr * 64 + ii * 16 + ml];
#pragma unroll
        for (int jj = 0; jj < 4; ++jj) bf[jj] = (long)Bf[ch * 128 + wc * 64 + jj * 16 + ml];
#pragma unroll
        for (int ii = 0; ii < 4; ++ii)
#pragma unroll
            for (int jj = 0; jj < 4; ++jj)
                acc[ii][jj] = __builtin_amdgcn_mfma_f32_16x16x32_fp8_fp8(af[ii], bf[jj], acc[ii][jj], 0, 0, 0);
    }

    const int pb = s_pb;
#pragma unroll
    for (int ii = 0; ii < 4; ++ii) {
        int la = wr * 64 + ii * 16 + q * 4;
#pragma unroll
        for (int jj = 0; jj < 4; ++jj) {
            int lb = wc * 64 + jj * 16 + ml;
            int b = tb * 128 + lb;
#pragma unroll
            for (int r = 0; r < 4; ++r) {
                int a = ta * 128 + la + r;
                if (a < n && b < n) {
                    float d2 = fmaf(-2.0f, acc[ii][jj][r], sqa[la + r] + sqb[lb]);
                    dpair[pb + a * n + b] = fast_sqrt(fmaxf(d2, FEPS));
                }
            }
        }
    }
}

// ---- node 4: S_rank = T - P (P from coalesced dpair rows) ----
__global__ void pairS_kernel(const float* __restrict__ T,
                             const int* __restrict__ cnt,
                             const int* __restrict__ mem2,
                             const float* __restrict__ dpair,
                             float* __restrict__ Srank) {
    __shared__ float Tl[CCAP];
    __shared__ int s_pb;
    const int tid = threadIdx.x;
    const int w = tid >> 6, lane = tid & 63;
    const int c = blockIdx.x;
    const int n = cnt[c];

    if (w == 0) {
        int v = cnt[lane];
        int v2 = v * v, s2 = v2;
#pragma unroll
        for (int o = 1; o < 64; o <<= 1) {
            int t2 = __shfl_up(s2, o, 64);
            if (lane >= o) s2 += t2;
        }
        if (lane == c) s_pb = s2 - v2;
    }
    for (int a = tid; a < n; a += 256) Tl[a] = T[mem2[c * CCAP + a]];
    __syncthreads();
    const int pb = s_pb;

    for (int a = w; a < n; a += 4) {
        const float* drow = dpair + pb + a * n;
        float p = 0.f;
        for (int b = lane; b < n; b += 64)
            if (b != a) p += __expf(1.0f - drow[b]);
#pragma unroll
        for (int off = 32; off > 0; off >>= 1) p += __shfl_down(p, off, 64);
        if (lane == 0) Srank[c * CCAP + a] = Tl[a] - p;   // exact cancellation
    }
}

// ---- node 5: loss over full n x n square + finalize ----
__global__ void pairB_kernel(const float* __restrict__ Srank,
                             const int* __restrict__ cnt,
                             const float* __restrict__ dpair,
                             float* __restrict__ loss_sum,
                             unsigned int* __restrict__ done,
                             float* __restrict__ out) {
    __shared__ float Sl[CCAP];
    __shared__ float redf[4];
    __shared__ int s_pb, s_tot;
    const int tid = threadIdx.x;
    const int w = tid >> 6, lane = tid & 63;
    const int c = blockIdx.x >> 2, q4 = blockIdx.x & 3;
    const int n = cnt[c];

    if (w == 0) {
        int v = cnt[lane];
        int v2 = v * v, s2 = v2;
#pragma unroll
        for (int o = 1; o < 64; o <<= 1) {
            int t2 = __shfl_up(s2, o, 64);
            if (lane >= o) s2 += t2;
        }
        if (lane == c) s_pb = s2 - v2;
        if (lane == 63) s_tot = s2;
    }
    for (int a = tid; a < n; a += 256) Sl[a] = Srank[c * CCAP + a];
    __syncthreads();
    const int pb = s_pb;

    float total = 0.f;
    for (int a = q4 * 4 + w; a < n; a += 16) {   // 16 row-streams across 4 blocks
        float Sa = Sl[a];
        const float* drow = dpair + pb + a * n;
        for (int b = lane; b < n; b += 64) {
            float d = (b == a) ? 1e-8f : drow[b];
            float J = __logf(Sa + Sl[b]) + d;
            float h = fmaxf(J, 0.0f);
            total += h * h;
        }
    }
#pragma unroll
    for (int off = 32; off > 0; off >>= 1) total += __shfl_down(total, off, 64);
    if (lane == 0) redf[w] = total;
    __syncthreads();
    if (tid == 0) {
        atomicAdd(loss_sum, redf[0] + redf[1] + redf[2] + redf[3]);
        __threadfence();
        unsigned int t = atomicAdd(done, 1u);
        if (t == gridDim.x - 1) {
            float tot = atomicAdd(loss_sum, 0.0f);
            out[0] = tot / (2.0f * (float)s_tot);
        }
    }
}

extern "C" void kernel_launch(void* const* d_in, const int* in_sizes, int n_in,
                              void* d_out, int out_size, void* d_ws, size_t ws_size,
                              hipStream_t stream) {
    const float* feat = (const float*)d_in[0];
    const int* labels = (const int*)d_in[1];

    float* ws = (float*)d_ws;
    float* T = ws + WS_T;
    int* cnt = (int*)(ws + WS_CNT);
    float* loss_sum = ws + WS_LOSS;
    unsigned int* done = (unsigned int*)(ws + WS_DONE);
    float* sq = ws + WS_SQ;
    int* mem2 = (int*)(ws + WS_MEM2);
    float* Srank = ws + WS_SRANK;
    unsigned char* G8 = (unsigned char*)(ws + WS_G16A);
    float* dpair = ws + WS_DP;
    float* outp = (float*)d_out;

    prep_bucket_kernel<<<NCLS + NPTS / 8, 256, 0, stream>>>(
        feat, labels, sq, G8, T, cnt, mem2, loss_sum, done);              // node 1
    gemm_T<<<NTILES, 256, 0, stream>>>(G8, sq, T);                        // node 2
    pairD_kernel<<<NCLS * 4, 256, 0, stream>>>(G8, sq, cnt, mem2, dpair); // node 3
    pairS_kernel<<<NCLS, 256, 0, stream>>>(T, cnt, mem2, dpair, Srank);   // node 4
    pairB_kernel<<<NCLS * 4, 256, 0, stream>>>(Srank, cnt, dpair,
                                               loss_sum, done, outp);     // node 5
}

// Round 20
// 118.236 us; speedup vs baseline: 1.4114x; 1.4114x over previous
//
#include <hip/hip_runtime.h>

#define NPTS 8192
#define DIM  128
#define NCLS 64
#define NT   64
#define NTILES (NT * (NT + 1) / 2)   // 2080 triangular tiles
#define CCAP 256                     // static per-class member capacity
#define FEPS 1e-16f

// ws layout (float elements). Kernels init all state (no host memset).
#define WS_S     0          // 8192 floats: S_i
#define WS_CNT   8192       // 64 ints (each class block writes its own)
#define WS_LOSS  8256       // 1 float
#define WS_DONE  8257       // 1 uint
#define WS_SQ    8258       // 8192 floats
#define WS_RANK  16515      // 8192 ints
#define WS_MEM2  24707      // 64*256 ints (static per-class member slots)
#define WS_G     41092      // byte 164368, 16B aligned; 1MB fp8 swizzled features
#define WS_DP    565380     // ~1.1M floats: canonical (hi*n+lo) per-pair distances

typedef float f32x4 __attribute__((ext_vector_type(4)));

__device__ inline float fast_sqrt(float x) {
    float r;
    asm("v_sqrt_f32 %0, %1" : "=v"(r) : "v"(x));
    return r;
}

// ---- node 1: class bucketing (blocks 0..63) + prep (blocks 64..1087) ----
// G layout (BYTE units, fp8 e4m3): tile t=i>>7 (16384 B) | chunk c=k>>3 (1024 B)
//                                  | m=i&127 (8 B) | k&7
__global__ void prep_bucket_kernel(const float* __restrict__ feat,
                                   const int* __restrict__ labels,
                                   float* __restrict__ sq,
                                   unsigned char* __restrict__ G,
                                   float* __restrict__ S,
                                   int* __restrict__ cnt,
                                   int* __restrict__ mem2,
                                   int* __restrict__ rank,
                                   float* __restrict__ loss_sum,
                                   unsigned int* __restrict__ done) {
    __shared__ int llab[NPTS];          // 32 KB
    __shared__ int scan_arr[256];
    __shared__ int wsum[4];

    const int tid = threadIdx.x;
    const int w = tid >> 6, lane = tid & 63;

    if (blockIdx.x >= NCLS) {
        // ---------------- prep path ----------------
        const int kl = lane & 31;          // float4 column
        const int rloc = lane >> 5;
        int i = (blockIdx.x - NCLS) * 8 + w * 2 + rloc;
        float4 v = ((const float4*)(feat + (size_t)i * DIM))[kl];
        unsigned lo = (unsigned)__builtin_amdgcn_cvt_pk_fp8_f32(v.x, v.y, 0, false) & 0xffffu;
        unsigned hi = (unsigned)__builtin_amdgcn_cvt_pk_fp8_f32(v.z, v.w, 0, false);
        unsigned word = lo | (hi << 16);
        int t = i >> 7, m = i & 127;
        int c = kl >> 1, pos = (kl & 1) * 4;
        *(unsigned*)&G[(size_t)t * 16384 + c * 1024 + m * 8 + pos] = word;
        float s = v.x * v.x + v.y * v.y + v.z * v.z + v.w * v.w;
#pragma unroll
        for (int msk = 1; msk <= 16; msk <<= 1) s += __shfl_xor(s, msk, 64);
        if (kl == 0) sq[i] = s;
        if (tid < 8) S[(blockIdx.x - NCLS) * 8 + tid] = 0.0f;
        return;
    }

    // ---------------- bucket path: one block per class, LDS-local ----------------
    const int c = blockIdx.x;
    {
        const uint4* L4 = (const uint4*)labels;
        uint4* S4 = (uint4*)llab;
#pragma unroll
        for (int k = 0; k < 8; ++k) S4[k * 256 + tid] = L4[k * 256 + tid];
    }
    if (c == 0 && tid == 0) { loss_sum[0] = 0.0f; done[0] = 0u; }
    __syncthreads();

    // lane-consecutive chunks (bank-conflict-free)
    int cntloc = 0;
#pragma unroll
    for (int k = 0; k < 32; ++k) cntloc += (llab[tid + 256 * k] == c) ? 1 : 0;
    scan_arr[tid] = cntloc;
    __syncthreads();

    int v = scan_arr[tid];
    int incl = v;
#pragma unroll
    for (int o = 1; o < 64; o <<= 1) {
        int t1 = __shfl_up(incl, o, 64);
        if (lane >= o) incl += t1;
    }
    if (lane == 63) wsum[w] = incl;
    __syncthreads();
    int wpre = 0;
#pragma unroll
    for (int ww = 0; ww < 4; ++ww) if (ww < w) wpre += wsum[ww];
    int excl = wpre + incl - v;

    int r = excl;
#pragma unroll
    for (int k = 0; k < 32; ++k) {
        int idx = tid + 256 * k;
        if (llab[idx] == c) {
            mem2[c * CCAP + r] = idx;
            rank[idx] = r;
            ++r;
        }
    }
    if (tid == 255) cnt[c] = excl + v;
}

// ---- node 2: triangular N^2 pass, fp8 MFMA, software-pipelined K-loop ----
__launch_bounds__(256, 4)
__global__ void gemm_S(const unsigned char* __restrict__ Gb,
                       const float* __restrict__ sq,
                       const int* __restrict__ labels,
                       const int* __restrict__ rank,
                       const int* __restrict__ cnt,
                       float* __restrict__ S,
                       float* __restrict__ dpair) {
    int p = blockIdx.x;
    float disc = 64.5f * 64.5f - 2.0f * (float)p;
    int bt = (int)(64.5f - fast_sqrt(disc));
    if (bt < 0) bt = 0; if (bt > 63) bt = 63;
    while (bt > 0 && (bt * NT - (bt * (bt - 1)) / 2) > p) --bt;
    while (((bt + 1) * NT - ((bt + 1) * bt) / 2) <= p) ++bt;
    int jt = bt + (p - (bt * NT - (bt * (bt - 1)) / 2));

    __shared__ float sqi[128], sqj[128];
    __shared__ int lli[128], llj[128], rki[128], rkj[128];
    __shared__ int s_cnt[NCLS], s_poff[NCLS];

    const int tid = threadIdx.x;
    const int w = tid >> 6, lane = tid & 63;
    const int wr = w >> 1, wc = w & 1;
    const int q = lane >> 4, ml = lane & 15;
    const int ib = bt * 128, jb = jt * 128;
    const bool diag = (bt == jt);

    if (tid < 128) {
        int i = ib + tid;
        sqi[tid] = sq[i]; lli[tid] = labels[i]; rki[tid] = rank[i];
    } else {
        int j = jb + tid - 128;
        sqj[tid - 128] = sq[j]; llj[tid - 128] = labels[j]; rkj[tid - 128] = rank[j];
    }
    if (w == 0) {                        // wave 0: load cnt + in-block poff scan
        int v = cnt[lane];
        s_cnt[lane] = v;
        int v2 = v * v, s2 = v2;
#pragma unroll
        for (int o = 1; o < 64; o <<= 1) {
            int t2 = __shfl_up(s2, o, 64);
            if (lane >= o) s2 += t2;
        }
        s_poff[lane] = s2 - v2;
    }
    __syncthreads();

    const long* A8 = (const long*)(Gb + (size_t)bt * 16384);
    const long* B8 = (const long*)(Gb + (size_t)jt * 16384);
    const int arow = wr * 64 + ml, brow = wc * 64 + ml;

    f32x4 acc[4][4];
#pragma unroll
    for (int a = 0; a < 4; ++a)
#pragma unroll
        for (int b = 0; b < 4; ++b) acc[a][b] = (f32x4){0.f, 0.f, 0.f, 0.f};

    // software-pipelined K-loop: prefetch phase s+1 while MFMAing phase s
    long af[4], bf[4], afn[4], bfn[4];
    {
        int kb = q * 128;
#pragma unroll
        for (int ii = 0; ii < 4; ++ii) af[ii] = A8[kb + arow + ii * 16];
#pragma unroll
        for (int jj = 0; jj < 4; ++jj) bf[jj] = B8[kb + brow + jj * 16];
    }
#pragma unroll
    for (int s = 0; s < 4; ++s) {
        if (s < 3) {
            int kb = ((s + 1) * 4 + q) * 128;
#pragma unroll
            for (int ii = 0; ii < 4; ++ii) afn[ii] = A8[kb + arow + ii * 16];
#pragma unroll
            for (int jj = 0; jj < 4; ++jj) bfn[jj] = B8[kb + brow + jj * 16];
        }
#pragma unroll
        for (int ii = 0; ii < 4; ++ii)
#pragma unroll
            for (int jj = 0; jj < 4; ++jj)
                acc[ii][jj] = __builtin_amdgcn_mfma_f32_16x16x32_fp8_fp8(af[ii], bf[jj], acc[ii][jj], 0, 0, 0);
        if (s < 3) {
#pragma unroll
            for (int ii = 0; ii < 4; ++ii) af[ii] = afn[ii];
#pragma unroll
            for (int jj = 0; jj < 4; ++jj) bf[jj] = bfn[jj];
        }
    }

    int cl[4], lcj[4], rbj[4]; float sj[4];
#pragma unroll
    for (int jj = 0; jj < 4; ++jj) {
        cl[jj] = wc * 64 + jj * 16 + ml;
        lcj[jj] = llj[cl[jj]]; sj[jj] = sqj[cl[jj]]; rbj[jj] = rkj[cl[jj]];
    }
    float colsum[4] = {0.f, 0.f, 0.f, 0.f};

#pragma unroll
    for (int ii = 0; ii < 4; ++ii) {
        int rl = wr * 64 + ii * 16 + q * 4;
        int lri[4], rai[4]; float si4[4];
#pragma unroll
        for (int r = 0; r < 4; ++r) {
            lri[r] = lli[rl + r]; si4[r] = sqi[rl + r]; rai[r] = rki[rl + r];
        }
        float rs[4] = {0.f, 0.f, 0.f, 0.f};
#pragma unroll
        for (int jj = 0; jj < 4; ++jj)
#pragma unroll
            for (int r = 0; r < 4; ++r) {
                float d2 = fmaf(-2.0f, acc[ii][jj][r], si4[r] + sj[jj]);
                float d = fast_sqrt(fmaxf(d2, FEPS));
                float e = __expf(1.0f - d);
                bool same = (lri[r] == lcj[jj]);
                float ep = same ? 0.0f : e;
                rs[r] += ep;
                colsum[jj] += ep;
                if (same) {
                    int i = ib + rl + r, j = jb + cl[jj];
                    if (i != j) {
                        int c = lri[r];
                        int n = s_cnt[c], base = s_poff[c];
                        int hi = max(rai[r], rbj[jj]), lo = min(rai[r], rbj[jj]);
                        dpair[base + hi * n + lo] = d;   // canonical, written once
                    }
                }
            }
#pragma unroll
        for (int m = 1; m < 16; m <<= 1)
#pragma unroll
            for (int r = 0; r < 4; ++r) rs[r] += __shfl_xor(rs[r], m, 64);
        if (ml == 0) {
#pragma unroll
            for (int r = 0; r < 4; ++r) atomicAdd(&S[ib + rl + r], rs[r]);
        }
    }
    if (!diag) {
#pragma unroll
        for (int m = 16; m < 64; m <<= 1)
#pragma unroll
            for (int jj = 0; jj < 4; ++jj) colsum[jj] += __shfl_xor(colsum[jj], m, 64);
        if (q == 0) {
#pragma unroll
            for (int jj = 0; jj < 4; ++jj)
                atomicAdd(&S[jb + cl[jj]], colsum[jj]);
        }
    }
}

// ---- node 3: per-class loss, 2 blocks/class (128 blocks), interleaved rows ----
__global__ void pairB_kernel(const float* __restrict__ S,
                             const int* __restrict__ cnt,
                             const int* __restrict__ mem2,
                             const float* __restrict__ dpair,
                             float* __restrict__ loss_sum,
                             unsigned int* __restrict__ done,
                             float* __restrict__ out) {
    __shared__ float Sg[CCAP];
    __shared__ float redf[4];
    __shared__ int s_pb, s_n, s_tot;
    const int tid = threadIdx.x;
    const int w = tid >> 6, lane = tid & 63;
    const int c = blockIdx.x >> 1, half = blockIdx.x & 1;

    if (w == 0) {                        // wave 0: poff scan
        int v = cnt[lane];
        int v2 = v * v, s2 = v2;
#pragma unroll
        for (int o = 1; o < 64; o <<= 1) {
            int t2 = __shfl_up(s2, o, 64);
            if (lane >= o) s2 += t2;
        }
        if (lane == c) { s_pb = s2 - v2; s_n = v; }
        if (lane == 63) s_tot = s2;
    }
    __syncthreads();
    const int n = s_n, pb = s_pb;

    for (int m_ = tid; m_ < n; m_ += 256) Sg[m_] = S[mem2[c * CCAP + m_]];
    __syncthreads();

    float total = 0.f;
    for (int a = half * 4 + w; a < n; a += 8) {   // 8 row-streams across 2 blocks
        float Sa = Sg[a];
        const float* drow = dpair + pb + a * n;
        for (int b = lane; b < a; b += 64) {
            float J = __logf(Sa + Sg[b]) + drow[b];   // coalesced row read
            float h = fmaxf(J, 0.0f);
            total += 2.0f * h * h;                    // symmetry
        }
        if (lane == 0) {                              // diagonal: d = sqrt(EPS)
            float J = __logf(2.0f * Sa) + 1e-8f;
            float h = fmaxf(J, 0.0f);
            total += h * h;
        }
    }
#pragma unroll
    for (int off = 32; off > 0; off >>= 1) total += __shfl_down(total, off, 64);
    if (lane == 0) redf[w] = total;
    __syncthreads();
    if (tid == 0) {
        atomicAdd(loss_sum, redf[0] + redf[1] + redf[2] + redf[3]);
        __threadfence();
        unsigned int t = atomicAdd(done, 1u);
        if (t == gridDim.x - 1) {
            float tot = atomicAdd(loss_sum, 0.0f);
            out[0] = tot / (2.0f * (float)s_tot);
        }
    }
}

extern "C" void kernel_launch(void* const* d_in, const int* in_sizes, int n_in,
                              void* d_out, int out_size, void* d_ws, size_t ws_size,
                              hipStream_t stream) {
    const float* feat = (const float*)d_in[0];
    const int* labels = (const int*)d_in[1];

    float* ws = (float*)d_ws;
    float* S = ws + WS_S;
    int* cnt = (int*)(ws + WS_CNT);
    float* loss_sum = ws + WS_LOSS;
    unsigned int* done = (unsigned int*)(ws + WS_DONE);
    float* sq = ws + WS_SQ;
    int* rank = (int*)(ws + WS_RANK);
    int* mem2 = (int*)(ws + WS_MEM2);
    unsigned char* G8 = (unsigned char*)(ws + WS_G);
    float* dpair = ws + WS_DP;
    float* outp = (float*)d_out;

    prep_bucket_kernel<<<NCLS + NPTS / 8, 256, 0, stream>>>(
        feat, labels, sq, G8, S, cnt, mem2, rank, loss_sum, done);        // node 1
    gemm_S<<<NTILES, 256, 0, stream>>>(G8, sq, labels, rank, cnt, S, dpair); // node 2
    pairB_kernel<<<NCLS * 2, 256, 0, stream>>>(S, cnt, mem2, dpair,
                                               loss_sum, done, outp);     // node 3
}

// Round 22
// 114.920 us; speedup vs baseline: 1.4521x; 1.0289x over previous
//
#include <hip/hip_runtime.h>

#define NPTS 8192
#define DIM  128
#define NCLS 64
#define NT   64
#define NTILES (NT * (NT + 1) / 2)   // 2080 triangular tiles
#define FEPS 1e-16f

// ws layout (float elements). Kernels init all state (no host memset).
#define WS_S     0          // 8192 floats: S_i (sorted order)
#define WS_CNT   8192       // 64 ints
#define WS_LOSS  8256       // 1 float
#define WS_DONE  8257       // 1 uint
#define WS_SQ    8258       // 8192 floats (sorted order)
#define WS_SPOS  16450      // 8192 ints: i -> sorted position
#define WS_LABS  24642      // 8192 ints: sorted-order labels
#define WS_G16A  32836      // 16B aligned (32836*4=131344=16*8209); 1MB fp8 = 262144 floats
#define WS_DP    294980     // = 32836 + 262144, AFTER G. ~1.1M floats upper-tri distances

typedef float f32x4 __attribute__((ext_vector_type(4)));

__device__ inline float fast_sqrt(float x) {
    float r;
    asm("v_sqrt_f32 %0, %1" : "=v"(r) : "v"(x));
    return r;
}

// ---- node 1: bucketing -> sorted positions (64 blocks, LDS-local, no cross-block deps) ----
__global__ void bucket_kernel(const int* __restrict__ labels,
                              int* __restrict__ cnt,
                              int* __restrict__ spos,
                              float* __restrict__ loss_sum,
                              unsigned int* __restrict__ done) {
    __shared__ int llab[NPTS];          // 32 KB
    __shared__ int wsum[4], wless[4];
    const int tid = threadIdx.x;
    const int w = tid >> 6, lane = tid & 63;
    const int c = blockIdx.x;

    {
        const uint4* L4 = (const uint4*)labels;
        uint4* S4 = (uint4*)llab;
#pragma unroll
        for (int k = 0; k < 8; ++k) S4[k * 256 + tid] = L4[k * 256 + tid];
    }
    if (c == 0 && tid == 0) { loss_sum[0] = 0.0f; done[0] = 0u; }
    __syncthreads();

    // lane-consecutive chunks (bank-conflict-free)
    int ce = 0, clt = 0;
#pragma unroll
    for (int k = 0; k < 32; ++k) {
        int l = llab[tid + 256 * k];
        ce += (l == c) ? 1 : 0;
        clt += (l < c) ? 1 : 0;
    }
    int incl = ce;
#pragma unroll
    for (int o = 1; o < 64; o <<= 1) {
        int t1 = __shfl_up(incl, o, 64);
        if (lane >= o) incl += t1;
    }
    if (lane == 63) wsum[w] = incl;
    int t = clt;
#pragma unroll
    for (int o = 1; o < 64; o <<= 1) t += __shfl_xor(t, o, 64);
    if (lane == 0) wless[w] = t;
    __syncthreads();

    int wpre = 0;
#pragma unroll
    for (int ww = 0; ww < 4; ++ww) if (ww < w) wpre += wsum[ww];
    const int offc = wless[0] + wless[1] + wless[2] + wless[3];

    int r = offc + wpre + incl - ce;
#pragma unroll
    for (int k = 0; k < 32; ++k) {
        int idx = tid + 256 * k;
        if (llab[idx] == c) { spos[idx] = r; ++r; }
    }
    if (tid == 0) cnt[c] = wsum[0] + wsum[1] + wsum[2] + wsum[3];
}

// ---- node 2: prep into SORTED order (1024 blocks) ----
// G layout (BYTE units, fp8 e4m3): tile t=sp>>7 (16384 B) | chunk c=k>>3 (1024 B)
//                                  | m=sp&127 (8 B) | k&7
__global__ void prep_kernel(const float* __restrict__ feat,
                            const int* __restrict__ labels,
                            const int* __restrict__ spos,
                            float* __restrict__ sq,
                            unsigned char* __restrict__ G,
                            float* __restrict__ S,
                            int* __restrict__ labs) {
    const int tid = threadIdx.x;
    const int w = tid >> 6, lane = tid & 63;
    const int kl = lane & 31;
    const int rloc = lane >> 5;
    int i = blockIdx.x * 8 + w * 2 + rloc;
    int sp = spos[i];
    float4 v = ((const float4*)(feat + (size_t)i * DIM))[kl];
    unsigned lo = (unsigned)__builtin_amdgcn_cvt_pk_fp8_f32(v.x, v.y, 0, false) & 0xffffu;
    unsigned hi = (unsigned)__builtin_amdgcn_cvt_pk_fp8_f32(v.z, v.w, 0, false);
    unsigned word = lo | (hi << 16);
    int t = sp >> 7, m = sp & 127;
    int c = kl >> 1, pos = (kl & 1) * 4;
    *(unsigned*)&G[(size_t)t * 16384 + c * 1024 + m * 8 + pos] = word;
    float s = v.x * v.x + v.y * v.y + v.z * v.z + v.w * v.w;
#pragma unroll
    for (int msk = 1; msk <= 16; msk <<= 1) s += __shfl_xor(s, msk, 64);
    if (kl == 0) { sq[sp] = s; labs[sp] = labels[i]; }
    if (tid < 8) S[blockIdx.x * 8 + tid] = 0.0f;
}

// ---- node 3: triangular N^2 pass; lean epilogue except class-boundary tiles ----
__launch_bounds__(256, 4)
__global__ void gemm_S(const unsigned char* __restrict__ Gb,
                       const float* __restrict__ sq,
                       const int* __restrict__ labs,
                       const int* __restrict__ cnt,
                       float* __restrict__ S,
                       float* __restrict__ dpair) {
    int p = blockIdx.x;
    float disc = 64.5f * 64.5f - 2.0f * (float)p;
    int bt = (int)(64.5f - fast_sqrt(disc));
    if (bt < 0) bt = 0; if (bt > 63) bt = 63;
    while (bt > 0 && (bt * NT - (bt * (bt - 1)) / 2) > p) --bt;
    while (((bt + 1) * NT - ((bt + 1) * bt) / 2) <= p) ++bt;
    int jt = bt + (p - (bt * NT - (bt * (bt - 1)) / 2));

    __shared__ float sqi[128], sqj[128];
    __shared__ int lli[128], llj[128];
    __shared__ int s_cnt[NCLS], s_offs[NCLS], s_poff[NCLS];

    const int tid = threadIdx.x;
    const int w = tid >> 6, lane = tid & 63;
    const int wr = w >> 1, wc = w & 1;
    const int q = lane >> 4, ml = lane & 15;
    const int ib = bt * 128, jb = jt * 128;
    const bool diag = (bt == jt);

    if (tid < 128) {
        int i = ib + tid;
        sqi[tid] = sq[i]; lli[tid] = labs[i];
    } else {
        int j = jb + tid - 128;
        sqj[tid - 128] = sq[j]; llj[tid - 128] = labs[j];
    }
    if (w == 0) {                        // wave 0: scan cnt -> offs, poff
        int v = cnt[lane];
        s_cnt[lane] = v;
        int v2 = v * v, s1 = v, s2 = v2;
#pragma unroll
        for (int o = 1; o < 64; o <<= 1) {
            int t1 = __shfl_up(s1, o, 64);
            int t2 = __shfl_up(s2, o, 64);
            if (lane >= o) { s1 += t1; s2 += t2; }
        }
        s_offs[lane] = s1 - v;
        s_poff[lane] = s2 - v2;
    }
    __syncthreads();

    const bool boundary = diag || (lli[127] == llj[0]);   // sorted: overlap iff edges match

    const long* A8 = (const long*)(Gb + (size_t)bt * 16384);
    const long* B8 = (const long*)(Gb + (size_t)jt * 16384);

    f32x4 acc[4][4];
#pragma unroll
    for (int a = 0; a < 4; ++a)
#pragma unroll
        for (int b = 0; b < 4; ++b) acc[a][b] = (f32x4){0.f, 0.f, 0.f, 0.f};

#pragma unroll
    for (int s = 0; s < 4; ++s) {
        long af[4], bf[4];
        int kbase = (s * 4 + q) * 128;
#pragma unroll
        for (int ii = 0; ii < 4; ++ii) af[ii] = A8[kbase + wr * 64 + ii * 16 + ml];
#pragma unroll
        for (int jj = 0; jj < 4; ++jj) bf[jj] = B8[kbase + wc * 64 + jj * 16 + ml];
#pragma unroll
        for (int ii = 0; ii < 4; ++ii)
#pragma unroll
            for (int jj = 0; jj < 4; ++jj)
                acc[ii][jj] = __builtin_amdgcn_mfma_f32_16x16x32_fp8_fp8(af[ii], bf[jj], acc[ii][jj], 0, 0, 0);
    }

    int cl[4]; float sj[4];
#pragma unroll
    for (int jj = 0; jj < 4; ++jj) {
        cl[jj] = wc * 64 + jj * 16 + ml;
        sj[jj] = sqj[cl[jj]];
    }
    float colsum[4] = {0.f, 0.f, 0.f, 0.f};

    if (!boundary) {
        // ---- lean epilogue: no same-label pairs possible in this tile ----
#pragma unroll
        for (int ii = 0; ii < 4; ++ii) {
            int rl = wr * 64 + ii * 16 + q * 4;
            float si4[4];
#pragma unroll
            for (int r = 0; r < 4; ++r) si4[r] = sqi[rl + r];
            float rs[4] = {0.f, 0.f, 0.f, 0.f};
#pragma unroll
            for (int jj = 0; jj < 4; ++jj)
#pragma unroll
                for (int r = 0; r < 4; ++r) {
                    float d2 = fmaf(-2.0f, acc[ii][jj][r], si4[r] + sj[jj]);
                    float d = fast_sqrt(fmaxf(d2, FEPS));
                    float e = __expf(1.0f - d);
                    rs[r] += e;
                    colsum[jj] += e;
                }
#pragma unroll
            for (int m = 1; m < 16; m <<= 1)
#pragma unroll
                for (int r = 0; r < 4; ++r) rs[r] += __shfl_xor(rs[r], m, 64);
            if (ml == 0) {
#pragma unroll
                for (int r = 0; r < 4; ++r) atomicAdd(&S[ib + rl + r], rs[r]);
            }
        }
        // lean tiles are never diagonal -> always accumulate column sums
#pragma unroll
        for (int m = 16; m < 64; m <<= 1)
#pragma unroll
            for (int jj = 0; jj < 4; ++jj) colsum[jj] += __shfl_xor(colsum[jj], m, 64);
        if (q == 0) {
#pragma unroll
            for (int jj = 0; jj < 4; ++jj)
                atomicAdd(&S[jb + cl[jj]], colsum[jj]);
        }
    } else {
        // ---- full epilogue: label predicate + canonical dpair writes ----
        int lcj[4];
#pragma unroll
        for (int jj = 0; jj < 4; ++jj) lcj[jj] = llj[cl[jj]];
#pragma unroll
        for (int ii = 0; ii < 4; ++ii) {
            int rl = wr * 64 + ii * 16 + q * 4;
            int lri[4]; float si4[4];
#pragma unroll
            for (int r = 0; r < 4; ++r) { lri[r] = lli[rl + r]; si4[r] = sqi[rl + r]; }
            float rs[4] = {0.f, 0.f, 0.f, 0.f};
#pragma unroll
            for (int jj = 0; jj < 4; ++jj)
#pragma unroll
                for (int r = 0; r < 4; ++r) {
                    float d2 = fmaf(-2.0f, acc[ii][jj][r], si4[r] + sj[jj]);
                    float d = fast_sqrt(fmaxf(d2, FEPS));
                    float e = __expf(1.0f - d);
                    bool same = (lri[r] == lcj[jj]);
                    float ep = same ? 0.0f : e;
                    rs[r] += ep;
                    colsum[jj] += ep;
                    if (same) {
                        int c2 = lri[r];
                        int n = s_cnt[c2], base = s_poff[c2], off = s_offs[c2];
                        int ra = ib + rl + r - off;
                        int rb = jb + cl[jj] - off;
                        if (ra < rb)
                            dpair[base + ra * n + rb] = d;   // upper-tri canonical,
                    }                                        // lane-contiguous in rb
                }
#pragma unroll
            for (int m = 1; m < 16; m <<= 1)
#pragma unroll
                for (int r = 0; r < 4; ++r) rs[r] += __shfl_xor(rs[r], m, 64);
            if (ml == 0) {
#pragma unroll
                for (int r = 0; r < 4; ++r) atomicAdd(&S[ib + rl + r], rs[r]);
            }
        }
        if (!diag) {
#pragma unroll
            for (int m = 16; m < 64; m <<= 1)
#pragma unroll
                for (int jj = 0; jj < 4; ++jj) colsum[jj] += __shfl_xor(colsum[jj], m, 64);
            if (q == 0) {
#pragma unroll
                for (int jj = 0; jj < 4; ++jj)
                    atomicAdd(&S[jb + cl[jj]], colsum[jj]);
            }
        }
    }
}

// ---- node 4: per-class loss, 4 blocks/class, contiguous S + coalesced dpair rows ----
__global__ void pairB_kernel(const float* __restrict__ S,
                             const int* __restrict__ cnt,
                             const float* __restrict__ dpair,
                             float* __restrict__ loss_sum,
                             unsigned int* __restrict__ done,
                             float* __restrict__ out) {
    __shared__ float Sg[256];
    __shared__ float redf[4];
    __shared__ int s_pb, s_n, s_off, s_tot;
    const int tid = threadIdx.x;
    const int w = tid >> 6, lane = tid & 63;
    const int c = blockIdx.x >> 2, q4 = blockIdx.x & 3;

    if (w == 0) {                        // wave 0: scan cnt -> off, poff
        int v = cnt[lane];
        int v2 = v * v, s1 = v, s2 = v2;
#pragma unroll
        for (int o = 1; o < 64; o <<= 1) {
            int t1 = __shfl_up(s1, o, 64);
            int t2 = __shfl_up(s2, o, 64);
            if (lane >= o) { s1 += t1; s2 += t2; }
        }
        if (lane == c) { s_pb = s2 - v2; s_off = s1 - v; s_n = v; }
        if (lane == 63) s_tot = s2;
    }
    __syncthreads();
    const int n = s_n, pb = s_pb, off = s_off;

    for (int m_ = tid; m_ < n; m_ += 256) Sg[m_] = S[off + m_];   // contiguous
    __syncthreads();

    float total = 0.f;
    for (int a = q4 * 4 + w; a < n; a += 16) {   // 16 row-streams across 4 blocks
        float Sa = Sg[a];
        const float* drow = dpair + pb + a * n;
        for (int b = lane; b < n; b += 64) {
            if (b > a) {
                float J = __logf(Sa + Sg[b]) + drow[b];   // coalesced upper-tri read
                float h = fmaxf(J, 0.0f);
                total += 2.0f * h * h;                    // symmetry
            }
        }
        if (lane == 0) {                                  // diagonal: d = sqrt(EPS)
            float J = __logf(2.0f * Sa) + 1e-8f;
            float h = fmaxf(J, 0.0f);
            total += h * h;
        }
    }
#pragma unroll
    for (int off2 = 32; off2 > 0; off2 >>= 1) total += __shfl_down(total, off2, 64);
    if (lane == 0) redf[w] = total;
    __syncthreads();
    if (tid == 0) {
        atomicAdd(loss_sum, redf[0] + redf[1] + redf[2] + redf[3]);
        __threadfence();
        unsigned int t = atomicAdd(done, 1u);
        if (t == gridDim.x - 1) {
            float tot = atomicAdd(loss_sum, 0.0f);
            out[0] = tot / (2.0f * (float)s_tot);
        }
    }
}

extern "C" void kernel_launch(void* const* d_in, const int* in_sizes, int n_in,
                              void* d_out, int out_size, void* d_ws, size_t ws_size,
                              hipStream_t stream) {
    const float* feat = (const float*)d_in[0];
    const int* labels = (const int*)d_in[1];

    float* ws = (float*)d_ws;
    float* S = ws + WS_S;
    int* cnt = (int*)(ws + WS_CNT);
    float* loss_sum = ws + WS_LOSS;
    unsigned int* done = (unsigned int*)(ws + WS_DONE);
    float* sq = ws + WS_SQ;
    int* spos = (int*)(ws + WS_SPOS);
    int* labs = (int*)(ws + WS_LABS);
    unsigned char* G8 = (unsigned char*)(ws + WS_G16A);
    float* dpair = ws + WS_DP;
    float* outp = (float*)d_out;

    bucket_kernel<<<NCLS, 256, 0, stream>>>(labels, cnt, spos, loss_sum, done);   // node 1
    prep_kernel<<<NPTS / 8, 256, 0, stream>>>(feat, labels, spos, sq, G8, S, labs); // node 2
    gemm_S<<<NTILES, 256, 0, stream>>>(G8, sq, labs, cnt, S, dpair);              // node 3
    pairB_kernel<<<NCLS * 4, 256, 0, stream>>>(S, cnt, dpair, loss_sum, done, outp); // node 4
}